// Round 4
// baseline (116.393 us; speedup 1.0000x reference)
//
#include <hip/hip_runtime.h>
#include <hip/hip_bf16.h>

// BlockTopK: x [8192, 8192] fp32, blocks of 4 along dim 1, top-2 per block,
// output {0,1} fp32 mask, same shape.
//
// One thread per 4-element block: float4 load -> 12 compares -> float4 store.
// Streaming, zero-reuse -> non-temporal loads/stores; 4x unroll per iteration
// so each wave keeps 4 KiB of loads in flight (hide ~900cy HBM latency).
// NOTE: __builtin_nontemporal_* requires a NATIVE vector type (ext_vector_type).
//
// Tie-break matches jax.lax.top_k (stable: lower index wins on equal values):
//   rank_i = #{ j : v_j > v_i  ||  (v_j == v_i && j < i) };  mask_i = rank_i < 2.

typedef float f32x4 __attribute__((ext_vector_type(4)));

__device__ __forceinline__ f32x4 topk_mask4(f32x4 v) {
  float a0 = v.x, a1 = v.y, a2 = v.z, a3 = v.w;
  int r0 = (a1 > a0) + (a2 > a0) + (a3 > a0);
  int r1 = (a0 >= a1) + (a2 > a1) + (a3 > a1);
  int r2 = (a0 >= a2) + (a1 >= a2) + (a3 > a2);
  int r3 = (a0 >= a3) + (a1 >= a3) + (a2 >= a3);
  f32x4 m;
  m.x = (r0 < 2) ? 1.0f : 0.0f;
  m.y = (r1 < 2) ? 1.0f : 0.0f;
  m.z = (r2 < 2) ? 1.0f : 0.0f;
  m.w = (r3 < 2) ? 1.0f : 0.0f;
  return m;
}

__global__ __launch_bounds__(256) void blocktopk_kernel(
    const f32x4* __restrict__ xin, f32x4* __restrict__ mout, long long nblocks) {
  const long long stride = (long long)gridDim.x * blockDim.x;
  long long i = (long long)blockIdx.x * blockDim.x + threadIdx.x;

  // main loop: 4 independent float4 streams in flight per iteration
  for (; i + 3 * stride < nblocks; i += 4 * stride) {
    f32x4 v0 = __builtin_nontemporal_load(&xin[i]);
    f32x4 v1 = __builtin_nontemporal_load(&xin[i + stride]);
    f32x4 v2 = __builtin_nontemporal_load(&xin[i + 2 * stride]);
    f32x4 v3 = __builtin_nontemporal_load(&xin[i + 3 * stride]);
    f32x4 m0 = topk_mask4(v0);
    f32x4 m1 = topk_mask4(v1);
    f32x4 m2 = topk_mask4(v2);
    f32x4 m3 = topk_mask4(v3);
    __builtin_nontemporal_store(m0, &mout[i]);
    __builtin_nontemporal_store(m1, &mout[i + stride]);
    __builtin_nontemporal_store(m2, &mout[i + 2 * stride]);
    __builtin_nontemporal_store(m3, &mout[i + 3 * stride]);
  }
  // tail (unused for 8192x8192, kept for generality)
  for (; i < nblocks; i += stride) {
    f32x4 v0 = __builtin_nontemporal_load(&xin[i]);
    __builtin_nontemporal_store(topk_mask4(v0), &mout[i]);
  }
}

extern "C" void kernel_launch(void* const* d_in, const int* in_sizes, int n_in,
                              void* d_out, int out_size, void* d_ws, size_t ws_size,
                              hipStream_t stream) {
  const f32x4* x = (const f32x4*)d_in[0];
  f32x4* out = (f32x4*)d_out;
  const long long n = (long long)in_sizes[0];    // 8192*8192
  const long long nblocks = n / 4;               // 16,777,216 float4 blocks

  const int threads = 256;
  long long want = (nblocks + threads - 1) / threads;
  int blocks = (int)(want < 2048 ? want : 2048); // 8 blocks/CU x 256 CU -> 32 waves/CU
  blocktopk_kernel<<<blocks, threads, 0, stream>>>(x, out, nblocks);
}

// Round 5
// 86.597 us; speedup vs baseline: 1.3441x; 1.3441x over previous
//
#include <hip/hip_runtime.h>
#include <hip/hip_bf16.h>

// BlockTopK: x [8192, 8192] fp32, blocks of 4 along dim 1, top-2 per block,
// output {0,1} fp32 mask, same shape.
//
// One thread per 4-element block, 1:1 grid (no loop): float4 nt-load ->
// 12 compares -> float4 nt-store. Pure-TLP structure mirrors the 6.3 TB/s
// float4-copy microbenchmark; R4 showed deep per-thread unroll at grid-stride
// distance REGRESSES (too many concurrent DRAM streams).
//
// Tie-break matches jax.lax.top_k (stable: lower index wins on equal values):
//   rank_i = #{ j : v_j > v_i  ||  (v_j == v_i && j < i) };  mask_i = rank_i < 2.

typedef float f32x4 __attribute__((ext_vector_type(4)));

__device__ __forceinline__ f32x4 topk_mask4(f32x4 v) {
  float a0 = v.x, a1 = v.y, a2 = v.z, a3 = v.w;
  int r0 = (a1 > a0) + (a2 > a0) + (a3 > a0);
  int r1 = (a0 >= a1) + (a2 > a1) + (a3 > a1);
  int r2 = (a0 >= a2) + (a1 >= a2) + (a3 > a2);
  int r3 = (a0 >= a3) + (a1 >= a3) + (a2 >= a3);
  f32x4 m;
  m.x = (r0 < 2) ? 1.0f : 0.0f;
  m.y = (r1 < 2) ? 1.0f : 0.0f;
  m.z = (r2 < 2) ? 1.0f : 0.0f;
  m.w = (r3 < 2) ? 1.0f : 0.0f;
  return m;
}

__global__ __launch_bounds__(256) void blocktopk_kernel(
    const f32x4* __restrict__ xin, f32x4* __restrict__ mout, long long nblocks) {
  long long i = (long long)blockIdx.x * blockDim.x + threadIdx.x;
  if (i < nblocks) {
    f32x4 v = __builtin_nontemporal_load(&xin[i]);
    __builtin_nontemporal_store(topk_mask4(v), &mout[i]);
  }
}

extern "C" void kernel_launch(void* const* d_in, const int* in_sizes, int n_in,
                              void* d_out, int out_size, void* d_ws, size_t ws_size,
                              hipStream_t stream) {
  const f32x4* x = (const f32x4*)d_in[0];
  f32x4* out = (f32x4*)d_out;
  const long long n = (long long)in_sizes[0];    // 8192*8192
  const long long nblocks = n / 4;               // 16,777,216 float4 blocks

  const int threads = 256;
  long long blocks = (nblocks + threads - 1) / threads;  // 65536 — 1:1, pure TLP
  blocktopk_kernel<<<(int)blocks, threads, 0, stream>>>(x, out, nblocks);
}